// Round 6
// baseline (251.618 us; speedup 1.0000x reference)
//
#include <hip/hip_runtime.h>
#include <hip/hip_bf16.h>
#include <stdint.h>

#define T_ 2
#define N_ 4096
#define D_ 1024
#define E_ 8
#define O_ 1024

#define BM 128
#define BN 128
#define BK 64          // K elements per LDS tile (128 B rows)
#define GEMM_GRID 1024 // persistent blocks; workctr starts here

typedef __attribute__((ext_vector_type(8))) short short8;
typedef __attribute__((ext_vector_type(4))) float f32x4;

#define AS1 __attribute__((address_space(1)))
#define AS3 __attribute__((address_space(3)))

// async global->LDS, 16B per lane; LDS dest = base + lane*16 (wave-uniform base)
__device__ inline void gld16(const unsigned short* g, unsigned short* l) {
    __builtin_amdgcn_global_load_lds((const AS1 unsigned int*)g,
                                     (AS3 unsigned int*)l, 16, 0, 0);
}

__device__ inline unsigned short f2bf(float f) {
    union { float f; unsigned u; } v; v.f = f;
    unsigned r = v.u + 0x7fff + ((v.u >> 16) & 1);  // RNE
    return (unsigned short)(r >> 16);
}

// ---------------------------------------------------------------------------
// Kernel 1: gating + x->bf16. No atomics. 8 tokens/block (2/wave), grid=1024
// (round-5 had 256 blocks -> too little parallelism for the LDS-read chains).
// ---------------------------------------------------------------------------
__global__ __launch_bounds__(256) void gate_kernel(
    const float* __restrict__ x, const float* __restrict__ Wg,
    unsigned short* __restrict__ xb,
    int* __restrict__ route, float2* __restrict__ gpair)
{
    __shared__ __align__(16) float WgT[E_][D_];   // 32 KB

    int tid = threadIdx.x;
    int wave = tid >> 6, lane = tid & 63;
    int token0 = blockIdx.x * 8;
    int t = token0 >> 12;                 // 8 consecutive tokens share t
    const float* wgb = Wg + (size_t)t * D_ * E_;

#pragma unroll
    for (int r = 0; r < 8; ++r) {
        int f = r * 1024 + tid * 4;       // flat Wg index; (d=f>>3, e=f&7)
        float4 v = *(const float4*)(wgb + f);
        WgT[f & 7][f >> 3]             = v.x;
        WgT[(f + 1) & 7][(f + 1) >> 3] = v.y;
        WgT[(f + 2) & 7][(f + 2) >> 3] = v.z;
        WgT[(f + 3) & 7][(f + 3) >> 3] = v.w;
    }
    __syncthreads();

#pragma unroll
    for (int tl = 0; tl < 2; ++tl) {
        int token = token0 + wave * 2 + tl;
        const float* xrow = x + (size_t)token * D_;

        float4 xv[4];
#pragma unroll
        for (int c = 0; c < 4; ++c)
            xv[c] = *(const float4*)(xrow + c * 256 + lane * 4);

        float acc[E_] = {0.f, 0.f, 0.f, 0.f, 0.f, 0.f, 0.f, 0.f};
#pragma unroll
        for (int c = 0; c < 4; ++c) {
            int d0 = c * 256 + lane * 4;
            unsigned lo = f2bf(xv[c].x) | ((unsigned)f2bf(xv[c].y) << 16);
            unsigned hi = f2bf(xv[c].z) | ((unsigned)f2bf(xv[c].w) << 16);
            *(uint2*)(&xb[(size_t)token * D_ + d0]) = make_uint2(lo, hi);
#pragma unroll
            for (int e = 0; e < E_; ++e) {
                float4 w = *(const float4*)(&WgT[e][d0]);
                acc[e] += xv[c].x * w.x + xv[c].y * w.y + xv[c].z * w.z + xv[c].w * w.w;
            }
        }
#pragma unroll
        for (int off = 1; off < 64; off <<= 1) {
#pragma unroll
            for (int e = 0; e < E_; ++e) acc[e] += __shfl_xor(acc[e], off, 64);
        }

        if (lane == 0) {
            // top-2, lowest-index-first on ties (matches jax.lax.top_k)
            float best = acc[0]; int bi = 0;
#pragma unroll
            for (int e = 1; e < E_; ++e) if (acc[e] > best) { best = acc[e]; bi = e; }
            float sec = -INFINITY; int si = 0;
#pragma unroll
            for (int e = 0; e < E_; ++e) if (e != bi && acc[e] > sec) { sec = acc[e]; si = e; }
            float s = best + sec + 1e-9f;
            route[token] = bi | (si << 8);
            gpair[token] = make_float2(best / s, sec / s);
        }
    }
}

// ---------------------------------------------------------------------------
// Kernel 1b: deterministic stream compaction, one block per (t,e) group.
// toklist entry = n | (slot<<16); slot = 0 if e is token's primary expert.
// Also initializes the gemm work-stealing counter.
// ---------------------------------------------------------------------------
__global__ __launch_bounds__(256) void build_lists(
    const int* __restrict__ route, const float2* __restrict__ gpair,
    int* __restrict__ toklist, float* __restrict__ gatelist,
    int* __restrict__ counts, int* __restrict__ workctr)
{
    int g = blockIdx.x;              // t*8 + e
    int t = g >> 3, e = g & 7;
    int tid = threadIdx.x;
    int wave = tid >> 6, lane = tid & 63;
    if (g == 0 && tid == 0) *workctr = GEMM_GRID;  // steals continue after static range

    __shared__ int waveSum[4];
    __shared__ int base;
    if (tid == 0) base = 0;

    for (int c = 0; c < N_; c += 256) {
        int n = c + tid;
        int r = route[t * N_ + n];
        int e0 = r & 255, e1 = (r >> 8) & 255;
        bool sel = (e0 == e) || (e1 == e);
        unsigned long long b = __ballot(sel);
        int pre  = __popcll(b & ((1ull << lane) - 1ull));
        if (lane == 0) waveSum[wave] = __popcll(b);
        __syncthreads();
        int woff = 0;
#pragma unroll
        for (int w = 0; w < 4; ++w) woff += (w < wave) ? waveSum[w] : 0;
        int total = waveSum[0] + waveSum[1] + waveSum[2] + waveSum[3];
        if (sel) {
            int p = base + woff + pre;
            int slot = (e0 == e) ? 0 : 1;
            toklist[g * N_ + p] = n | (slot << 16);
            float2 gp = gpair[t * N_ + n];
            gatelist[g * N_ + p] = (e0 == e) ? gp.x : gp.y;
        }
        __syncthreads();
        if (tid == 0) base += total;
    }
    __syncthreads();
    if (tid == 0) counts[g] = base;
}

// ---------------------------------------------------------------------------
// Kernel 2: We fp32 [e][d][o] -> bf16 packed [(e*8+o/128)*128 + o%128][d].
// ---------------------------------------------------------------------------
__global__ __launch_bounds__(256) void pack_kernel(
    const float* __restrict__ We, unsigned short* __restrict__ Wbp)
{
    __shared__ __align__(16) unsigned short P[64 * 136];

    int b = blockIdx.x;
    int e  = b >> 7;
    int oy = (b & 127) >> 3;   // 0..15
    int dz = b & 7;            // 0..7
    int o0 = oy * 64, d0 = dz * 128;
    int tid = threadIdx.x;

#pragma unroll
    for (int r = 0; r < 32; ++r) {
        int lin = r * 256 + tid;
        int dd = lin >> 6, oo = lin & 63;
        P[oo * 136 + dd] = f2bf(We[((size_t)(e * D_ + d0 + dd)) * O_ + o0 + oo]);
    }
    __syncthreads();

#pragma unroll
    for (int w = 0; w < 4; ++w) {
        int ci = w * 256 + tid;      // 1024 16B-chunks
        int oo = ci >> 4, dc = ci & 15;
        uint4 v = *(const uint4*)&P[oo * 136 + dc * 8];
        int o = o0 + oo;
        int ot = o >> 7, nn = o & 127;
        unsigned short* dst =
            Wbp + ((size_t)((e * 8 + ot) * 128 + nn)) * D_ + d0 + dc * 8;
        *(uint4*)dst = v;
    }
}

// ---------------------------------------------------------------------------
// Kernel 3: grouped GEMM, round 6. Persistent hybrid static+steal scheduling
// (round-5 counters: Occupancy 20% w/ 3/4 phantom blocks = imbalance).
// BK=64 (16 iters, half the barrier drains). XOR granule swizzle: row r's
// 16B-granule g lives at LDS position g^(r&7) -> conflict-free frag reads
// (round-5: 4.39M SQ_LDS_BANK_CONFLICT from lanes sharing q=lane>>4).
// Epilogue: bf16 slot trick (no atomics), both halves of every out word
// written -> no out memset needed.
// ---------------------------------------------------------------------------
__global__ __launch_bounds__(256, 4) void moe_gemm(
    const unsigned short* __restrict__ xb,   // [T*N][D] bf16
    const unsigned short* __restrict__ Wbp,  // [(e*8+ot)*128+n][D] bf16
    const int* __restrict__ toklist, const float* __restrict__ gatelist,
    const int* __restrict__ counts, int* __restrict__ workctr,
    float* __restrict__ out)
{
    __shared__ __align__(16) unsigned short As[BM * BK];  // 16 KB
    __shared__ __align__(16) unsigned short Bs[BN * BK];  // 16 KB
    __shared__ int   tokS[BM];
    __shared__ float gateS[BM];
    __shared__ int   cntS[16], mtp[17];
    __shared__ int   curIdx;

    int tid = threadIdx.x;
    int wave = tid >> 6, lane = tid & 63;

    if (tid < 16) cntS[tid] = counts[tid];
    __syncthreads();
    if (tid == 0) {
        int s = 0; mtp[0] = 0;
#pragma unroll
        for (int g = 0; g < 16; ++g) { s += (cntS[g] + BM - 1) >> 7; mtp[g + 1] = s; }
    }
    __syncthreads();
    int totalItems = mtp[16] * 8;

    // staging lane map: 8 rows x 8 granules per chunk; granule xor-swizzled
    int lr = lane >> 3;              // row within 8-row chunk
    int sg = (lane & 7) ^ lr;        // source granule (perm within 128B segment)
    // frag map
    int fr = lane & 15, q = lane >> 4;
    int wm = (wave & 1) * 64, wn = (wave >> 1) * 64;

    int idx = blockIdx.x;
    while (idx < totalItems) {
        int tile = idx >> 3, ot = idx & 7;
        int g = 0;
        while (mtp[g + 1] <= tile) ++g;       // uniform across block
        int t = g >> 3;
        int cnt = cntS[g];
        int m0 = (tile - mtp[g]) * BM;

        if (tid < BM) {
            int r = m0 + tid;
            tokS[tid]  = (r < cnt) ? toklist[g * N_ + r]  : -1;
            gateS[tid] = (r < cnt) ? gatelist[g * N_ + r] : 0.f;
        }
        __syncthreads();

        // per-thread global bases: wave w stages A-chunks 4w..4w+3, B same
        const unsigned short* ag[4];
        const unsigned short* bg[4];
        const unsigned short* wb = Wbp + ((size_t)((g & 7) * 8 + ot) * 128) * D_;
#pragma unroll
        for (int i = 0; i < 4; ++i) {
            int row = (wave * 4 + i) * 8 + lr;
            int tok = max(tokS[row], 0) & 0xFFFF;
            ag[i] = xb + ((size_t)(t * N_ + tok)) * D_ + sg * 8;
            bg[i] = wb + (size_t)row * D_ + sg * 8;
        }
        unsigned short* la = &As[wave * 4 * 512];   // 4 chunks x 512 shorts
        unsigned short* lb = &Bs[wave * 4 * 512];

        f32x4 acc[4][4];
#pragma unroll
        for (int mi = 0; mi < 4; ++mi)
#pragma unroll
            for (int ni = 0; ni < 4; ++ni) acc[mi][ni] = (f32x4){0.f, 0.f, 0.f, 0.f};

        for (int k0 = 0; k0 < D_; k0 += BK) {
#pragma unroll
            for (int i = 0; i < 4; ++i) {
                gld16(ag[i] + k0, la + i * 512);
                gld16(bg[i] + k0, lb + i * 512);
            }
            __syncthreads();   // drains vmcnt + all waves staged

#pragma unroll
            for (int kk = 0; kk < 2; ++kk) {
                short8 af[4], bf[4];
#pragma unroll
                for (int mi = 0; mi < 4; ++mi) {
                    int r = wm + mi * 16 + fr;
                    af[mi] = *(const short8*)(&As[r * BK + (((kk * 4 + q) ^ (fr & 7)) * 8)]);
                }
#pragma unroll
                for (int ni = 0; ni < 4; ++ni) {
                    int r = wn + ni * 16 + fr;
                    bf[ni] = *(const short8*)(&Bs[r * BK + (((kk * 4 + q) ^ (fr & 7)) * 8)]);
                }
#pragma unroll
                for (int mi = 0; mi < 4; ++mi)
#pragma unroll
                    for (int ni = 0; ni < 4; ++ni)
                        acc[mi][ni] = __builtin_amdgcn_mfma_f32_16x16x32_bf16(
                            af[mi], bf[ni], acc[mi][ni], 0, 0, 0);
            }
            __syncthreads();   // frags consumed before next stage overwrites
        }

        // epilogue: C/D layout col = lane&15, row = q*4 + reg  [m89/m91]
        float* outb = out + (size_t)t * N_ * O_;
        int ncol = ot * 128 + wn + fr;
#pragma unroll
        for (int mi = 0; mi < 4; ++mi) {
#pragma unroll
            for (int r = 0; r < 4; ++r) {
                int ml = wm + mi * 16 + q * 4 + r;
                int ent = tokS[ml];
                if (ent >= 0) {
                    int tok  = ent & 0xFFFF;
                    int slot = ent >> 16;
                    float gate = gateS[ml];
#pragma unroll
                    for (int ni = 0; ni < 4; ++ni) {
                        unsigned short* p =
                            (unsigned short*)(outb + (size_t)tok * O_ + ncol + ni * 16);
                        p[slot] = f2bf(gate * acc[mi][ni][r]);
                    }
                }
            }
        }

        if (tid == 0) curIdx = atomicAdd(workctr, 1);
        __syncthreads();       // epilogue tokS reads done + curIdx visible
        idx = curIdx;
    }
}

// ---------------------------------------------------------------------------
// Kernel 4: combine the two bf16 slot halves of each out word into fp32.
// ---------------------------------------------------------------------------
__global__ __launch_bounds__(256) void combine_kernel(float* __restrict__ out)
{
    size_t i = ((size_t)blockIdx.x * 256 + threadIdx.x) * 4;
    unsigned* po = (unsigned*)out;
    uint4 v = *(uint4*)(po + i);
    float4 r;
    union { unsigned u; float f; } a, b;
#define CMB(comp, src) a.u = (src) << 16; b.u = (src) & 0xFFFF0000u; comp = a.f + b.f
    CMB(r.x, v.x); CMB(r.y, v.y); CMB(r.z, v.z); CMB(r.w, v.w);
#undef CMB
    *(float4*)(out + i) = r;
}

// ---------------------------------------------------------------------------
extern "C" void kernel_launch(void* const* d_in, const int* in_sizes, int n_in,
                              void* d_out, int out_size, void* d_ws, size_t ws_size,
                              hipStream_t stream)
{
    const float* x  = (const float*)d_in[0];
    const float* Wg = (const float*)d_in[1];
    const float* We = (const float*)d_in[2];
    float* out = (float*)d_out;

    char* ws = (char*)d_ws;
    unsigned short* xb   = (unsigned short*)(ws);               // 16,777,216 B
    unsigned short* Wbp  = (unsigned short*)(ws + 16777216);    // 16,777,216 B
    int*   toklist       = (int*)  (ws + 33554432);             //    262,144 B
    float* gatelist      = (float*)(ws + 33816576);             //    262,144 B
    int*   counts        = (int*)  (ws + 34078720);             //        256 B
    int*   workctr       = (int*)  (ws + 34078976);             //        256 B
    int*   route         = (int*)  (ws + 34079232);             //     32,768 B
    float2* gpair        = (float2*)(ws + 34112000);            //     65,536 B

    gate_kernel<<<(T_ * N_) / 8, 256, 0, stream>>>(x, Wg, xb, route, gpair);
    build_lists<<<T_ * E_, 256, 0, stream>>>(route, gpair, toklist, gatelist,
                                             counts, workctr);
    pack_kernel<<<E_ * (O_ / 64) * (D_ / 128), 256, 0, stream>>>(We, Wbp);
    moe_gemm<<<GEMM_GRID, 256, 0, stream>>>(xb, Wbp, toklist, gatelist,
                                            counts, workctr, out);
    combine_kernel<<<((size_t)T_ * N_ * O_) / (256 * 4), 256, 0, stream>>>(out);
}

// Round 7
// 250.820 us; speedup vs baseline: 1.0032x; 1.0032x over previous
//
#include <hip/hip_runtime.h>
#include <hip/hip_bf16.h>
#include <stdint.h>

#define T_ 2
#define N_ 4096
#define D_ 1024
#define E_ 8
#define O_ 1024

#define BM 128
#define BN 128
#define BK 64   // 128-B LDS rows: granule-xor swizzle is conflict-free (r6: 0 conflicts)

typedef __attribute__((ext_vector_type(8))) short short8;
typedef __attribute__((ext_vector_type(4))) float f32x4;

#define AS1 __attribute__((address_space(1)))
#define AS3 __attribute__((address_space(3)))

// async global->LDS, 16B per lane; LDS dest = base + lane*16 (wave-uniform base)
__device__ inline void gld16(const unsigned short* g, unsigned short* l) {
    __builtin_amdgcn_global_load_lds((const AS1 unsigned int*)g,
                                     (AS3 unsigned int*)l, 16, 0, 0);
}

__device__ inline unsigned short f2bf(float f) {
    union { float f; unsigned u; } v; v.f = f;
    unsigned r = v.u + 0x7fff + ((v.u >> 16) & 1);  // RNE
    return (unsigned short)(r >> 16);
}

// ---------------------------------------------------------------------------
// Kernel 1: gating + x->bf16. No atomics. 8 tokens/block, grid=1024.
// ---------------------------------------------------------------------------
__global__ __launch_bounds__(256) void gate_kernel(
    const float* __restrict__ x, const float* __restrict__ Wg,
    unsigned short* __restrict__ xb,
    int* __restrict__ route, float2* __restrict__ gpair)
{
    __shared__ __align__(16) float WgT[E_][D_];   // 32 KB

    int tid = threadIdx.x;
    int wave = tid >> 6, lane = tid & 63;
    int token0 = blockIdx.x * 8;
    int t = token0 >> 12;                 // 8 consecutive tokens share t
    const float* wgb = Wg + (size_t)t * D_ * E_;

#pragma unroll
    for (int r = 0; r < 8; ++r) {
        int f = r * 1024 + tid * 4;       // flat Wg index; (d=f>>3, e=f&7)
        float4 v = *(const float4*)(wgb + f);
        WgT[f & 7][f >> 3]             = v.x;
        WgT[(f + 1) & 7][(f + 1) >> 3] = v.y;
        WgT[(f + 2) & 7][(f + 2) >> 3] = v.z;
        WgT[(f + 3) & 7][(f + 3) >> 3] = v.w;
    }
    __syncthreads();

#pragma unroll
    for (int tl = 0; tl < 2; ++tl) {
        int token = token0 + wave * 2 + tl;
        const float* xrow = x + (size_t)token * D_;

        float4 xv[4];
#pragma unroll
        for (int c = 0; c < 4; ++c)
            xv[c] = *(const float4*)(xrow + c * 256 + lane * 4);

        float acc[E_] = {0.f, 0.f, 0.f, 0.f, 0.f, 0.f, 0.f, 0.f};
#pragma unroll
        for (int c = 0; c < 4; ++c) {
            int d0 = c * 256 + lane * 4;
            unsigned lo = f2bf(xv[c].x) | ((unsigned)f2bf(xv[c].y) << 16);
            unsigned hi = f2bf(xv[c].z) | ((unsigned)f2bf(xv[c].w) << 16);
            *(uint2*)(&xb[(size_t)token * D_ + d0]) = make_uint2(lo, hi);
#pragma unroll
            for (int e = 0; e < E_; ++e) {
                float4 w = *(const float4*)(&WgT[e][d0]);
                acc[e] += xv[c].x * w.x + xv[c].y * w.y + xv[c].z * w.z + xv[c].w * w.w;
            }
        }
#pragma unroll
        for (int off = 1; off < 64; off <<= 1) {
#pragma unroll
            for (int e = 0; e < E_; ++e) acc[e] += __shfl_xor(acc[e], off, 64);
        }

        if (lane == 0) {
            // top-2, lowest-index-first on ties (matches jax.lax.top_k)
            float best = acc[0]; int bi = 0;
#pragma unroll
            for (int e = 1; e < E_; ++e) if (acc[e] > best) { best = acc[e]; bi = e; }
            float sec = -INFINITY; int si = 0;
#pragma unroll
            for (int e = 0; e < E_; ++e) if (e != bi && acc[e] > sec) { sec = acc[e]; si = e; }
            float s = best + sec + 1e-9f;
            route[token] = bi | (si << 8);
            gpair[token] = make_float2(best / s, sec / s);
        }
    }
}

// ---------------------------------------------------------------------------
// Kernel 1b: deterministic stream compaction, one block per (t,e) group.
// toklist entry = n | (slot<<16); slot = 0 if e is token's primary expert.
// ---------------------------------------------------------------------------
__global__ __launch_bounds__(256) void build_lists(
    const int* __restrict__ route, const float2* __restrict__ gpair,
    int* __restrict__ toklist, float* __restrict__ gatelist,
    int* __restrict__ counts)
{
    int g = blockIdx.x;              // t*8 + e
    int t = g >> 3, e = g & 7;
    int tid = threadIdx.x;
    int wave = tid >> 6, lane = tid & 63;

    __shared__ int waveSum[4];
    __shared__ int base;
    if (tid == 0) base = 0;

    for (int c = 0; c < N_; c += 256) {
        int n = c + tid;
        int r = route[t * N_ + n];
        int e0 = r & 255, e1 = (r >> 8) & 255;
        bool sel = (e0 == e) || (e1 == e);
        unsigned long long b = __ballot(sel);
        int pre  = __popcll(b & ((1ull << lane) - 1ull));
        if (lane == 0) waveSum[wave] = __popcll(b);
        __syncthreads();
        int woff = 0;
#pragma unroll
        for (int w = 0; w < 4; ++w) woff += (w < wave) ? waveSum[w] : 0;
        int total = waveSum[0] + waveSum[1] + waveSum[2] + waveSum[3];
        if (sel) {
            int p = base + woff + pre;
            int slot = (e0 == e) ? 0 : 1;
            toklist[g * N_ + p] = n | (slot << 16);
            float2 gp = gpair[t * N_ + n];
            gatelist[g * N_ + p] = (e0 == e) ? gp.x : gp.y;
        }
        __syncthreads();
        if (tid == 0) base += total;
    }
    __syncthreads();
    if (tid == 0) counts[g] = base;
}

// ---------------------------------------------------------------------------
// Kernel 2: We fp32 [e][d][o] -> bf16 packed [(e*8+o/128)*128 + o%128][d].
// ---------------------------------------------------------------------------
__global__ __launch_bounds__(256) void pack_kernel(
    const float* __restrict__ We, unsigned short* __restrict__ Wbp)
{
    __shared__ __align__(16) unsigned short P[64 * 136];

    int b = blockIdx.x;
    int e  = b >> 7;
    int oy = (b & 127) >> 3;   // 0..15
    int dz = b & 7;            // 0..7
    int o0 = oy * 64, d0 = dz * 128;
    int tid = threadIdx.x;

#pragma unroll
    for (int r = 0; r < 32; ++r) {
        int lin = r * 256 + tid;
        int dd = lin >> 6, oo = lin & 63;
        P[oo * 136 + dd] = f2bf(We[((size_t)(e * D_ + d0 + dd)) * O_ + o0 + oo]);
    }
    __syncthreads();

#pragma unroll
    for (int w = 0; w < 4; ++w) {
        int ci = w * 256 + tid;      // 1024 16B-chunks
        int oo = ci >> 4, dc = ci & 15;
        uint4 v = *(const uint4*)&P[oo * 136 + dc * 8];
        int o = o0 + oo;
        int ot = o >> 7, nn = o & 127;
        unsigned short* dst =
            Wbp + ((size_t)((e * 8 + ot) * 128 + nn)) * D_ + d0 + dc * 8;
        *(uint4*)dst = v;
    }
}

// ---------------------------------------------------------------------------
// Kernel 3: grouped GEMM, round 7 = r5 scheduling (static 4096 grid, XCD
// swizzle: 37 MB FETCH measured; r6 work-stealing thrashed L2 -> 187 MB)
// + r6 inner loop (BK=64, 16 barrier drains; XOR granule swizzle: 0 bank
// conflicts measured) + r5 slot-trick epilogue (no atomics, no memset).
// ---------------------------------------------------------------------------
__global__ __launch_bounds__(256, 4) void moe_gemm(
    const unsigned short* __restrict__ xb,   // [T*N][D] bf16
    const unsigned short* __restrict__ Wbp,  // [(e*8+ot)*128+n][D] bf16
    const int* __restrict__ toklist, const float* __restrict__ gatelist,
    const int* __restrict__ counts, float* __restrict__ out)
{
    // flat id -> (m-tile, o-tile, group) with XCD affinity: xcd = lin & 7
    int lin = blockIdx.x + (blockIdx.y << 5) + (blockIdx.z << 8);  // 0..4095
    int xcd = lin & 7, slot_ = lin >> 3;      // 512 slots per XCD
    int mt = slot_ & 31;
    int pr = xcd * 16 + (slot_ >> 5);         // 0..127 = (ot, g) pair
    int ot = pr & 7;
    int g  = pr >> 3;                         // t*8 + e
    int t  = g >> 3;

    int cnt = counts[g];
    int m0 = mt * BM;
    if (m0 >= cnt) return;

    __shared__ __align__(16) unsigned short As[BM * BK];  // 16 KB
    __shared__ __align__(16) unsigned short Bs[BN * BK];  // 16 KB
    __shared__ int   tokS[BM];
    __shared__ float gateS[BM];

    int tid = threadIdx.x;
    if (tid < BM) {
        int r = m0 + tid;
        tokS[tid]  = (r < cnt) ? toklist[g * N_ + r]  : -1;
        gateS[tid] = (r < cnt) ? gatelist[g * N_ + r] : 0.f;
    }
    __syncthreads();

    int wave = tid >> 6, lane = tid & 63;
    // staging: wave w stages 8-row chunks 4w..4w+3 of A and B.
    // lane l covers row lr of its chunk, LDS granule (l&7), source granule
    // sg = (l&7)^lr  ->  LDS position p of row r holds granule p^(r&7).
    int lr = lane >> 3;
    int sg = (lane & 7) ^ lr;
    const unsigned short* ag[4];
    const unsigned short* bg[4];
    const unsigned short* wb = Wbp + ((size_t)((g & 7) * 8 + ot) * 128) * D_;
#pragma unroll
    for (int i = 0; i < 4; ++i) {
        int row = (wave * 4 + i) * 8 + lr;
        int tok = max(tokS[row], 0) & 0xFFFF;   // junk rows masked in epilogue
        ag[i] = xb + ((size_t)(t * N_ + tok)) * D_ + sg * 8;
        bg[i] = wb + (size_t)row * D_ + sg * 8;
    }
    unsigned short* la = &As[wave * 2048];   // 4 chunks x 512 shorts
    unsigned short* lb = &Bs[wave * 2048];

    int fr = lane & 15, q = lane >> 4;
    int wm = (wave & 1) * 64, wn = (wave >> 1) * 64;

    f32x4 acc[4][4];
#pragma unroll
    for (int mi = 0; mi < 4; ++mi)
#pragma unroll
        for (int ni = 0; ni < 4; ++ni) acc[mi][ni] = (f32x4){0.f, 0.f, 0.f, 0.f};

    for (int k0 = 0; k0 < D_; k0 += BK) {
#pragma unroll
        for (int i = 0; i < 4; ++i) {
            gld16(ag[i] + k0, la + i * 512);
            gld16(bg[i] + k0, lb + i * 512);
        }
        __syncthreads();   // drains vmcnt (loads landed) + all waves staged

#pragma unroll
        for (int kk = 0; kk < 2; ++kk) {
            short8 af[4], bf[4];
#pragma unroll
            for (int mi = 0; mi < 4; ++mi) {
                int r = wm + mi * 16 + fr;
                af[mi] = *(const short8*)(&As[r * BK + (((kk * 4 + q) ^ (fr & 7)) * 8)]);
            }
#pragma unroll
            for (int ni = 0; ni < 4; ++ni) {
                int r = wn + ni * 16 + fr;
                bf[ni] = *(const short8*)(&Bs[r * BK + (((kk * 4 + q) ^ (fr & 7)) * 8)]);
            }
#pragma unroll
            for (int mi = 0; mi < 4; ++mi)
#pragma unroll
                for (int ni = 0; ni < 4; ++ni)
                    acc[mi][ni] = __builtin_amdgcn_mfma_f32_16x16x32_bf16(
                        af[mi], bf[ni], acc[mi][ni], 0, 0, 0);
        }
        __syncthreads();   // frags consumed before next stage overwrites
    }

    // epilogue: C/D layout col = lane&15, row = q*4 + reg  [m89/m91]
    float* outb = out + (size_t)t * N_ * O_;
    int ncol = ot * 128 + wn + fr;
#pragma unroll
    for (int mi = 0; mi < 4; ++mi) {
#pragma unroll
        for (int r = 0; r < 4; ++r) {
            int ml = wm + mi * 16 + q * 4 + r;
            int ent = tokS[ml];
            if (ent >= 0) {
                int tok  = ent & 0xFFFF;
                int slot = ent >> 16;
                float gate = gateS[ml];
#pragma unroll
                for (int ni = 0; ni < 4; ++ni) {
                    unsigned short* p =
                        (unsigned short*)(outb + (size_t)tok * O_ + ncol + ni * 16);
                    p[slot] = f2bf(gate * acc[mi][ni][r]);
                }
            }
        }
    }
}

// ---------------------------------------------------------------------------
// Kernel 4: combine the two bf16 slot halves of each out word into fp32.
// ---------------------------------------------------------------------------
__global__ __launch_bounds__(256) void combine_kernel(float* __restrict__ out)
{
    size_t i = ((size_t)blockIdx.x * 256 + threadIdx.x) * 4;
    unsigned* po = (unsigned*)out;
    uint4 v = *(uint4*)(po + i);
    float4 r;
    union { unsigned u; float f; } a, b;
#define CMB(comp, src) a.u = (src) << 16; b.u = (src) & 0xFFFF0000u; comp = a.f + b.f
    CMB(r.x, v.x); CMB(r.y, v.y); CMB(r.z, v.z); CMB(r.w, v.w);
#undef CMB
    *(float4*)(out + i) = r;
}

// ---------------------------------------------------------------------------
extern "C" void kernel_launch(void* const* d_in, const int* in_sizes, int n_in,
                              void* d_out, int out_size, void* d_ws, size_t ws_size,
                              hipStream_t stream)
{
    const float* x  = (const float*)d_in[0];
    const float* Wg = (const float*)d_in[1];
    const float* We = (const float*)d_in[2];
    float* out = (float*)d_out;

    char* ws = (char*)d_ws;
    unsigned short* xb   = (unsigned short*)(ws);               // 16,777,216 B
    unsigned short* Wbp  = (unsigned short*)(ws + 16777216);    // 16,777,216 B
    int*   toklist       = (int*)  (ws + 33554432);             //    262,144 B
    float* gatelist      = (float*)(ws + 33816576);             //    262,144 B
    int*   counts        = (int*)  (ws + 34078720);             //        256 B
    int*   route         = (int*)  (ws + 34078976);             //     32,768 B
    float2* gpair        = (float2*)(ws + 34111744);            //     65,536 B

    gate_kernel<<<(T_ * N_) / 8, 256, 0, stream>>>(x, Wg, xb, route, gpair);
    build_lists<<<T_ * E_, 256, 0, stream>>>(route, gpair, toklist, gatelist, counts);
    pack_kernel<<<E_ * (O_ / 64) * (D_ / 128), 256, 0, stream>>>(We, Wbp);
    moe_gemm<<<dim3(N_ / BM, O_ / BN, T_ * E_), 256, 0, stream>>>(
        xb, Wbp, toklist, gatelist, counts, out);
    combine_kernel<<<((size_t)T_ * N_ * O_) / (256 * 4), 256, 0, stream>>>(out);
}

// Round 8
// 194.728 us; speedup vs baseline: 1.2922x; 1.2881x over previous
//
#include <hip/hip_runtime.h>
#include <hip/hip_bf16.h>
#include <stdint.h>

#define T_ 2
#define N_ 4096
#define D_ 1024
#define E_ 8
#define O_ 1024

#define BM 128
#define BN 128
#define BK 32   // 64-B LDS rows; granule-xor pos=q^(r&3) is conflict-free (8 words/bank exact)

typedef __attribute__((ext_vector_type(8))) short short8;
typedef __attribute__((ext_vector_type(4))) float f32x4;

#define AS1 __attribute__((address_space(1)))
#define AS3 __attribute__((address_space(3)))

// async global->LDS, 16B per lane; LDS dest = base + lane*16 (wave-uniform base)
__device__ inline void gld16(const unsigned short* g, unsigned short* l) {
    __builtin_amdgcn_global_load_lds((const AS1 unsigned int*)g,
                                     (AS3 unsigned int*)l, 16, 0, 0);
}

__device__ inline unsigned short f2bf(float f) {
    union { float f; unsigned u; } v; v.f = f;
    unsigned r = v.u + 0x7fff + ((v.u >> 16) & 1);  // RNE
    return (unsigned short)(r >> 16);
}

// ---------------------------------------------------------------------------
// Kernel 1: gating + x->bf16. No atomics. 8 tokens/block, grid=1024.
// ---------------------------------------------------------------------------
__global__ __launch_bounds__(256) void gate_kernel(
    const float* __restrict__ x, const float* __restrict__ Wg,
    unsigned short* __restrict__ xb,
    int* __restrict__ route, float2* __restrict__ gpair)
{
    __shared__ __align__(16) float WgT[E_][D_];   // 32 KB

    int tid = threadIdx.x;
    int wave = tid >> 6, lane = tid & 63;
    int token0 = blockIdx.x * 8;
    int t = token0 >> 12;                 // 8 consecutive tokens share t
    const float* wgb = Wg + (size_t)t * D_ * E_;

#pragma unroll
    for (int r = 0; r < 8; ++r) {
        int f = r * 1024 + tid * 4;       // flat Wg index; (d=f>>3, e=f&7)
        float4 v = *(const float4*)(wgb + f);
        WgT[f & 7][f >> 3]             = v.x;
        WgT[(f + 1) & 7][(f + 1) >> 3] = v.y;
        WgT[(f + 2) & 7][(f + 2) >> 3] = v.z;
        WgT[(f + 3) & 7][(f + 3) >> 3] = v.w;
    }
    __syncthreads();

#pragma unroll
    for (int tl = 0; tl < 2; ++tl) {
        int token = token0 + wave * 2 + tl;
        const float* xrow = x + (size_t)token * D_;

        float4 xv[4];
#pragma unroll
        for (int c = 0; c < 4; ++c)
            xv[c] = *(const float4*)(xrow + c * 256 + lane * 4);

        float acc[E_] = {0.f, 0.f, 0.f, 0.f, 0.f, 0.f, 0.f, 0.f};
#pragma unroll
        for (int c = 0; c < 4; ++c) {
            int d0 = c * 256 + lane * 4;
            unsigned lo = f2bf(xv[c].x) | ((unsigned)f2bf(xv[c].y) << 16);
            unsigned hi = f2bf(xv[c].z) | ((unsigned)f2bf(xv[c].w) << 16);
            *(uint2*)(&xb[(size_t)token * D_ + d0]) = make_uint2(lo, hi);
#pragma unroll
            for (int e = 0; e < E_; ++e) {
                float4 w = *(const float4*)(&WgT[e][d0]);
                acc[e] += xv[c].x * w.x + xv[c].y * w.y + xv[c].z * w.z + xv[c].w * w.w;
            }
        }
#pragma unroll
        for (int off = 1; off < 64; off <<= 1) {
#pragma unroll
            for (int e = 0; e < E_; ++e) acc[e] += __shfl_xor(acc[e], off, 64);
        }

        if (lane == 0) {
            // top-2, lowest-index-first on ties (matches jax.lax.top_k)
            float best = acc[0]; int bi = 0;
#pragma unroll
            for (int e = 1; e < E_; ++e) if (acc[e] > best) { best = acc[e]; bi = e; }
            float sec = -INFINITY; int si = 0;
#pragma unroll
            for (int e = 0; e < E_; ++e) if (e != bi && acc[e] > sec) { sec = acc[e]; si = e; }
            float s = best + sec + 1e-9f;
            route[token] = bi | (si << 8);
            gpair[token] = make_float2(best / s, sec / s);
        }
    }
}

// ---------------------------------------------------------------------------
// Kernel 1b: deterministic stream compaction, one block per (t,e) group.
// toklist entry = n | (slot<<16); slot = 0 if e is token's primary expert.
// ---------------------------------------------------------------------------
__global__ __launch_bounds__(256) void build_lists(
    const int* __restrict__ route, const float2* __restrict__ gpair,
    int* __restrict__ toklist, float* __restrict__ gatelist,
    int* __restrict__ counts)
{
    int g = blockIdx.x;              // t*8 + e
    int t = g >> 3, e = g & 7;
    int tid = threadIdx.x;
    int wave = tid >> 6, lane = tid & 63;

    __shared__ int waveSum[4];
    __shared__ int base;
    if (tid == 0) base = 0;

    for (int c = 0; c < N_; c += 256) {
        int n = c + tid;
        int r = route[t * N_ + n];
        int e0 = r & 255, e1 = (r >> 8) & 255;
        bool sel = (e0 == e) || (e1 == e);
        unsigned long long b = __ballot(sel);
        int pre  = __popcll(b & ((1ull << lane) - 1ull));
        if (lane == 0) waveSum[wave] = __popcll(b);
        __syncthreads();
        int woff = 0;
#pragma unroll
        for (int w = 0; w < 4; ++w) woff += (w < wave) ? waveSum[w] : 0;
        int total = waveSum[0] + waveSum[1] + waveSum[2] + waveSum[3];
        if (sel) {
            int p = base + woff + pre;
            int slot = (e0 == e) ? 0 : 1;
            toklist[g * N_ + p] = n | (slot << 16);
            float2 gp = gpair[t * N_ + n];
            gatelist[g * N_ + p] = (e0 == e) ? gp.x : gp.y;
        }
        __syncthreads();
        if (tid == 0) base += total;
    }
    __syncthreads();
    if (tid == 0) counts[g] = base;
}

// ---------------------------------------------------------------------------
// Kernel 2: We fp32 [e][d][o] -> bf16 packed [(e*8+o/128)*128 + o%128][d].
// ---------------------------------------------------------------------------
__global__ __launch_bounds__(256) void pack_kernel(
    const float* __restrict__ We, unsigned short* __restrict__ Wbp)
{
    __shared__ __align__(16) unsigned short P[64 * 136];

    int b = blockIdx.x;
    int e  = b >> 7;
    int oy = (b & 127) >> 3;   // 0..15
    int dz = b & 7;            // 0..7
    int o0 = oy * 64, d0 = dz * 128;
    int tid = threadIdx.x;

#pragma unroll
    for (int r = 0; r < 32; ++r) {
        int lin = r * 256 + tid;
        int dd = lin >> 6, oo = lin & 63;
        P[oo * 136 + dd] = f2bf(We[((size_t)(e * D_ + d0 + dd)) * O_ + o0 + oo]);
    }
    __syncthreads();

#pragma unroll
    for (int w = 0; w < 4; ++w) {
        int ci = w * 256 + tid;      // 1024 16B-chunks
        int oo = ci >> 4, dc = ci & 15;
        uint4 v = *(const uint4*)&P[oo * 136 + dc * 8];
        int o = o0 + oo;
        int ot = o >> 7, nn = o & 127;
        unsigned short* dst =
            Wbp + ((size_t)((e * 8 + ot) * 128 + nn)) * D_ + d0 + dc * 8;
        *(uint4*)dst = v;
    }
}

// ---------------------------------------------------------------------------
// Kernel 3: grouped GEMM, round 8 = r5's exact footprint (BK=32, 17.4 KB LDS
// -> ~8 blocks/CU; 37 MB FETCH / 65 MB WRITE measured) + conflict-free
// granule-xor swizzle pos=q^(r&3) (r5 paid 4.4M conflicts; r6 proved xor=0)
// + mt-SLOWEST dispatch order: real tiles dispatch first (phantoms drain at
// the end), and each XCD runs all 16 of its (g,ot) pairs at the same mt
// concurrently -> A-rows shared by 8 ot in L2 (r7's mt-fast + low occupancy
// broke this: 106 MB FETCH).  1-D grid 4096, xcd = lin%8 invariant.
// ---------------------------------------------------------------------------
__global__ __launch_bounds__(256) void moe_gemm(
    const unsigned short* __restrict__ xb,   // [T*N][D] bf16
    const unsigned short* __restrict__ Wbp,  // [(e*8+ot)*128+n][D] bf16
    const int* __restrict__ toklist, const float* __restrict__ gatelist,
    const int* __restrict__ counts, float* __restrict__ out)
{
    int lin = blockIdx.x;            // 0..4095
    int mt  = lin >> 7;              // slowest: real tiles (mt < ~9) first
    int u   = lin & 127;
    int xcd = u & 7;                 // == lin % 8 == hw XCD round-robin
    int v   = u >> 3;                // 0..15
    int g   = 2 * xcd + (v >> 3);    // xcd owns groups {2x, 2x+1}
    int ot  = v & 7;
    int t   = g >> 3;

    int cnt = counts[g];
    int m0 = mt * BM;
    if (m0 >= cnt) return;

    __shared__ __align__(16) unsigned short As[BM * BK];  // 8 KB
    __shared__ __align__(16) unsigned short Bs[BN * BK];  // 8 KB
    __shared__ int   tokS[BM];
    __shared__ float gateS[BM];

    int tid = threadIdx.x;
    if (tid < BM) {
        int r = m0 + tid;
        tokS[tid]  = (r < cnt) ? toklist[g * N_ + r]  : -1;
        gateS[tid] = (r < cnt) ? gatelist[g * N_ + r] : 0.f;
    }
    __syncthreads();

    int wave = tid >> 6, lane = tid & 63;
    // staging: wave w stages 16-row chunks 2w, 2w+1 of A and B.
    // lane l -> row (l>>2) of chunk, LDS granule (l&3); source granule
    // sg = (l&3)^((l>>2)&3), so LDS pos p of row r holds granule p^(r&3).
    int lr = lane >> 2;
    int sg = (lane & 3) ^ (lr & 3);
    int c0 = wave * 2, c1 = c0 + 1;
    int ar0 = c0 * 16 + lr, ar1 = c1 * 16 + lr;
    int tok0 = max(tokS[ar0], 0) & 0xFFFF;   // junk rows masked in epilogue
    int tok1 = max(tokS[ar1], 0) & 0xFFFF;
    const unsigned short* ag0 = xb + ((size_t)(t * N_ + tok0)) * D_ + sg * 8;
    const unsigned short* ag1 = xb + ((size_t)(t * N_ + tok1)) * D_ + sg * 8;
    const unsigned short* wb  = Wbp + ((size_t)((g & 7) * 8 + ot) * 128) * D_;
    const unsigned short* bg0 = wb + (size_t)ar0 * D_ + sg * 8;
    const unsigned short* bg1 = wb + (size_t)ar1 * D_ + sg * 8;
    unsigned short* la0 = &As[c0 * 512];     // 16 rows x 32 shorts
    unsigned short* la1 = &As[c1 * 512];
    unsigned short* lb0 = &Bs[c0 * 512];
    unsigned short* lb1 = &Bs[c1 * 512];

    int fr = lane & 15, q = lane >> 4;
    int wm = (wave & 1) * 64, wn = (wave >> 1) * 64;
    int fp = (q ^ (fr & 3)) * 8;             // swizzled frag granule offset

    f32x4 acc[4][4];
#pragma unroll
    for (int mi = 0; mi < 4; ++mi)
#pragma unroll
        for (int ni = 0; ni < 4; ++ni) acc[mi][ni] = (f32x4){0.f, 0.f, 0.f, 0.f};

    for (int k0 = 0; k0 < D_; k0 += BK) {
        gld16(ag0 + k0, la0);
        gld16(ag1 + k0, la1);
        gld16(bg0 + k0, lb0);
        gld16(bg1 + k0, lb1);
        __syncthreads();   // drains vmcnt (loads landed) + all waves staged

        short8 af[4], bf[4];
#pragma unroll
        for (int mi = 0; mi < 4; ++mi)
            af[mi] = *(const short8*)(&As[(wm + mi * 16 + fr) * BK + fp]);
#pragma unroll
        for (int ni = 0; ni < 4; ++ni)
            bf[ni] = *(const short8*)(&Bs[(wn + ni * 16 + fr) * BK + fp]);
#pragma unroll
        for (int mi = 0; mi < 4; ++mi)
#pragma unroll
            for (int ni = 0; ni < 4; ++ni)
                acc[mi][ni] = __builtin_amdgcn_mfma_f32_16x16x32_bf16(
                    af[mi], bf[ni], acc[mi][ni], 0, 0, 0);
        __syncthreads();   // frags consumed before next stage overwrites
    }

    // epilogue: C/D layout col = lane&15, row = q*4 + reg  [m89/m91]
    float* outb = out + (size_t)t * N_ * O_;
    int ncol = ot * 128 + wn + fr;
#pragma unroll
    for (int mi = 0; mi < 4; ++mi) {
#pragma unroll
        for (int r = 0; r < 4; ++r) {
            int ml = wm + mi * 16 + q * 4 + r;
            int ent = tokS[ml];
            if (ent >= 0) {
                int tok  = ent & 0xFFFF;
                int slot = ent >> 16;
                float gate = gateS[ml];
#pragma unroll
                for (int ni = 0; ni < 4; ++ni) {
                    unsigned short* p =
                        (unsigned short*)(outb + (size_t)tok * O_ + ncol + ni * 16);
                    p[slot] = f2bf(gate * acc[mi][ni][r]);
                }
            }
        }
    }
}

// ---------------------------------------------------------------------------
// Kernel 4: combine the two bf16 slot halves of each out word into fp32.
// ---------------------------------------------------------------------------
__global__ __launch_bounds__(256) void combine_kernel(float* __restrict__ out)
{
    size_t i = ((size_t)blockIdx.x * 256 + threadIdx.x) * 4;
    unsigned* po = (unsigned*)out;
    uint4 v = *(uint4*)(po + i);
    float4 r;
    union { unsigned u; float f; } a, b;
#define CMB(comp, src) a.u = (src) << 16; b.u = (src) & 0xFFFF0000u; comp = a.f + b.f
    CMB(r.x, v.x); CMB(r.y, v.y); CMB(r.z, v.z); CMB(r.w, v.w);
#undef CMB
    *(float4*)(out + i) = r;
}

// ---------------------------------------------------------------------------
extern "C" void kernel_launch(void* const* d_in, const int* in_sizes, int n_in,
                              void* d_out, int out_size, void* d_ws, size_t ws_size,
                              hipStream_t stream)
{
    const float* x  = (const float*)d_in[0];
    const float* Wg = (const float*)d_in[1];
    const float* We = (const float*)d_in[2];
    float* out = (float*)d_out;

    char* ws = (char*)d_ws;
    unsigned short* xb   = (unsigned short*)(ws);               // 16,777,216 B
    unsigned short* Wbp  = (unsigned short*)(ws + 16777216);    // 16,777,216 B
    int*   toklist       = (int*)  (ws + 33554432);             //    262,144 B
    float* gatelist      = (float*)(ws + 33816576);             //    262,144 B
    int*   counts        = (int*)  (ws + 34078720);             //        256 B
    int*   route         = (int*)  (ws + 34078976);             //     32,768 B
    float2* gpair        = (float2*)(ws + 34111744);            //     65,536 B

    gate_kernel<<<(T_ * N_) / 8, 256, 0, stream>>>(x, Wg, xb, route, gpair);
    build_lists<<<T_ * E_, 256, 0, stream>>>(route, gpair, toklist, gatelist, counts);
    pack_kernel<<<E_ * (O_ / 64) * (D_ / 128), 256, 0, stream>>>(We, Wbp);
    moe_gemm<<<(N_ / BM) * 8 * (T_ * E_), 256, 0, stream>>>(
        xb, Wbp, toklist, gatelist, counts, out);
    combine_kernel<<<((size_t)T_ * N_ * O_) / (256 * 4), 256, 0, stream>>>(out);
}